// Round 12
// baseline (3151.400 us; speedup 1.0000x reference)
//
#include <hip/hip_runtime.h>
#include <stdint.h>

#define FP8_MAX 448.0f
#define BSQ 128          // quantization block size
#define TM 128
#define TN 256
#define NKB 32           // K / BSQ

typedef int   i32x4  __attribute__((ext_vector_type(4)));
typedef int   i32x8  __attribute__((ext_vector_type(8)));
typedef float f32x4v __attribute__((ext_vector_type(4)));
typedef float f32x16 __attribute__((ext_vector_type(16)));

typedef const __attribute__((address_space(1))) uint8_t* gptr_t;
typedef __attribute__((address_space(3))) uint8_t* lptr_t;

// 3-bit granule hash: 32-row fragment b128 reads spread evenly over all
// 8 granule-columns -> bank-minimal (verified: 0 conflicts rounds 3-11).
__device__ __forceinline__ int hsw(int row) { return (row ^ (row >> 3)) & 7; }

// ---------------- activation quantization: per (row, 128-block) ----------------
// scales written TRANSPOSED: sxT[kb*M + row]  (lane-linear gather in GEMM stage)
__global__ void act_quant_kernel(const float* __restrict__ x,
                                 uint8_t* __restrict__ xq,
                                 float* __restrict__ sxT,
                                 int M, int K) {
    int gid  = blockIdx.x * blockDim.x + threadIdx.x;
    int wave = gid >> 6;
    int lane = threadIdx.x & 63;
    int nkb  = K / BSQ;
    int row  = wave / nkb;
    int kb   = wave - row * nkb;
    if (row >= M) return;

    const float2 v = *(const float2*)(x + (size_t)row * K + kb * BSQ + lane * 2);
    float am = fmaxf(fabsf(v.x), fabsf(v.y));
#pragma unroll
    for (int off = 32; off >= 1; off >>= 1)
        am = fmaxf(am, __shfl_xor(am, off));

    float s = am / FP8_MAX;                    // matches reference: amax/448 in fp32
    if (lane == 0) sxT[(size_t)kb * M + row] = s;

    float q0 = (am > 0.f) ? v.x / s : 0.f;     // fp32 IEEE division, then RNE->e4m3
    float q1 = (am > 0.f) ? v.y / s : 0.f;
    int packed = __builtin_amdgcn_cvt_pk_fp8_f32(q0, q1, 0, false);
    *(uint16_t*)(xq + (size_t)row * K + kb * BSQ + lane * 2) = (uint16_t)(packed & 0xffff);
}

// ---------------- weight cast fp32(fp8-representable) -> e4m3 bytes ----------------
__global__ void weight_quant_kernel(const float* __restrict__ w,
                                    uint8_t* __restrict__ wq, size_t n) {
    size_t i = ((size_t)blockIdx.x * blockDim.x + threadIdx.x) * 4;
    if (i >= n) return;
    float4 v = *(const float4*)(w + i);
    int lo = __builtin_amdgcn_cvt_pk_fp8_f32(v.x, v.y, 0, false);
    int hi = __builtin_amdgcn_cvt_pk_fp8_f32(v.z, v.w, 0, false);
    *(uint32_t*)(wq + i) = (uint32_t)((lo & 0xffff) | (hi << 16));
}

// ---------------- 128x256 single-buffer MX GEMM, 4 waves x (128x64 tile) ----------------
// Lever: frag-reads per MFMA. Wave reads A-frags 16 + B-frags 8 = 24 b128 for
// 16 MFMAs (1.5/MFMA vs champion's 2.0). Per-CU LDS/step-pair unchanged
// (2313 cyc) but MFMA work doubles -> pipes balanced at ~2300 cyc.
// Registers: acc 128 (AGPR) + arch ~128 = 256 = exactly the 2-wave bin
// (R9 compiled this wave shape to 128 arch, zero spill).
__global__ __launch_bounds__(256, 2)
void fp8_gemm_mx(const uint8_t* __restrict__ Aq,   // [M][K] e4m3
                 const uint8_t* __restrict__ Bq,   // [N][K] e4m3
                 const float*  __restrict__ sxT,   // [K/128][M]  (transposed)
                 const float*  __restrict__ swg,   // [N/128][K/128]
                 float* __restrict__ out,          // [M][N]
                 int M, int N, int K) {
    __shared__ uint8_t As[TM * BSQ];         // 16 KB, granule-swizzled rows
    __shared__ uint8_t Bs[TN * BSQ];         // 32 KB
    __shared__ float   sxs[TM];              // 0.5 KB raw sx row

    const int tid  = threadIdx.x;
    const int lane = tid & 63;
    const int wx   = tid >> 6;               // 0..3, 64-col slice per wave
    const int brow = blockIdx.y * TM;
    const int bcol = blockIdx.x * TN;

    const int fl = lane & 31, hi = lane >> 5;

    // staging: LDS dest linear, global SOURCE pre-swizzled (involution)
    auto STAGE = [&](int kb) {
#pragma unroll
        for (int r = 0; r < 4; ++r) {        // A: 128 rows
            int slot = r * 256 + tid;          // 0..1023 16B-slots
            int row  = slot >> 3;              // 0..127
            int g    = (slot & 7) ^ hsw(row);
            const uint8_t* gA = Aq + (size_t)(brow + row) * K + kb * BSQ + g * 16;
            __builtin_amdgcn_global_load_lds((gptr_t)gA,
                (lptr_t)(As + (slot & ~63) * 16), 16, 0, 0);
        }
#pragma unroll
        for (int r = 0; r < 8; ++r) {        // B: 256 rows
            int slot = r * 256 + tid;          // 0..2047 16B-slots
            int row  = slot >> 3;              // 0..255
            int g    = (slot & 7) ^ hsw(row);
            const uint8_t* gB = Bq + (size_t)(bcol + row) * K + kb * BSQ + g * 16;
            __builtin_amdgcn_global_load_lds((gptr_t)gB,
                (lptr_t)(Bs + (slot & ~63) * 16), 16, 0, 0);
        }
        if (wx < 2) {                        // 128-float scale row, lane x 4B linear
            const float* gs = sxT + (size_t)kb * M + brow + wx * 64 + lane;
            __builtin_amdgcn_global_load_lds((gptr_t)(const uint8_t*)gs,
                (lptr_t)(sxs + wx * 64), 4, 0, 0);
        }
    };

    const f32x16 zz = {0.f,0.f,0.f,0.f, 0.f,0.f,0.f,0.f,
                       0.f,0.f,0.f,0.f, 0.f,0.f,0.f,0.f};
    f32x4v acc[4][2][4];                     // [fm][fn][q] -> 128 f32 (AGPR)
#pragma unroll
    for (int i = 0; i < 4; ++i)
#pragma unroll
        for (int j = 0; j < 2; ++j)
#pragma unroll
            for (int q = 0; q < 4; ++q) acc[i][j][q] = {0.f, 0.f, 0.f, 0.f};

    // prologue
    STAGE(0);
    __syncthreads();

    for (int kb = 0; kb < NKB; ++kb) {
        // wave-uniform weight scale for this wave's 64-col slice
        const float sw = swg[(size_t)((bcol >> 7) + (wx >> 1)) * NKB + kb];

        // B fragments (8 x b128), reused across all 4 fm-phases
        i32x8 bfr[2][2];
#pragma unroll
        for (int fn = 0; fn < 2; ++fn) {
            int row = wx * 64 + fn * 32 + fl;
            int hh  = hsw(row);
            const uint8_t* base = Bs + row * BSQ;
#pragma unroll
            for (int kh = 0; kh < 2; ++kh) {
                int g0 = kh * 4 + hi * 2;
                i32x4 lo = *(const i32x4*)(base + (((g0    ) ^ hh) << 4));
                i32x4 h4 = *(const i32x4*)(base + (((g0 + 1) ^ hh) << 4));
                bfr[fn][kh] = (i32x8){lo.x, lo.y, lo.z, lo.w, h4.x, h4.y, h4.z, h4.w};
            }
        }

#pragma unroll
        for (int fm = 0; fm < 4; ++fm) {
            int arow = fm * 32 + fl;
            int hh   = hsw(arow);
            const uint8_t* abase = As + arow * BSQ;
            i32x8 afr[2];
#pragma unroll
            for (int kh = 0; kh < 2; ++kh) {
                int g0 = kh * 4 + hi * 2;
                i32x4 lo = *(const i32x4*)(abase + (((g0    ) ^ hh) << 4));
                i32x4 h4 = *(const i32x4*)(abase + (((g0 + 1) ^ hh) << 4));
                afr[kh] = (i32x8){lo.x, lo.y, lo.z, lo.w, h4.x, h4.y, h4.z, h4.w};
            }
            // per-row scales (same-address broadcast reads) x wave-uniform sw
            f32x4v s4[4];
#pragma unroll
            for (int q = 0; q < 4; ++q) {
                s4[q] = *(const f32x4v*)&sxs[fm * 32 + q * 8 + hi * 4];
                s4[q] *= sw;
            }

#pragma unroll
            for (int fn = 0; fn < 2; ++fn) {
                // unit HW scales (e8m0 127 -> x1.0); exact fp32 fold below
                f32x16 p = __builtin_amdgcn_mfma_scale_f32_32x32x64_f8f6f4(
                    afr[0], bfr[fn][0], zz, 0, 0, 0, 127, 0, 127);
                p = __builtin_amdgcn_mfma_scale_f32_32x32x64_f8f6f4(
                    afr[1], bfr[fn][1], p, 0, 0, 0, 127, 0, 127);
#pragma unroll
                for (int q = 0; q < 4; ++q) {
                    f32x4v pq = {p[q * 4], p[q * 4 + 1], p[q * 4 + 2], p[q * 4 + 3]};
                    acc[fm][fn][q] += pq * s4[q];
                }
            }
        }

        // reads of this tile done -> restage (2-sync single-buffer loop; the
        // co-resident block computes through this block's stage drain)
        __syncthreads();
        if (kb + 1 < NKB) {
            STAGE(kb + 1);
            __syncthreads();
        }
    }

    // epilogue: C/D 32x32 layout col=lane&31, row=(reg&3)+8*(reg>>2)+4*(lane>>5)
    // nontemporal: 268MB streaming writes must not evict L3-resident fp8 panels
#pragma unroll
    for (int fm = 0; fm < 4; ++fm)
#pragma unroll
        for (int fn = 0; fn < 2; ++fn)
#pragma unroll
            for (int q = 0; q < 4; ++q)
#pragma unroll
                for (int j = 0; j < 4; ++j) {
                    int row = brow + fm * 32 + q * 8 + hi * 4 + j;
                    int col = bcol + wx * 64 + fn * 32 + fl;
                    __builtin_nontemporal_store(acc[fm][fn][q][j],
                                                &out[(size_t)row * N + col]);
                }
}

extern "C" void kernel_launch(void* const* d_in, const int* in_sizes, int n_in,
                              void* d_out, int out_size, void* d_ws, size_t ws_size,
                              hipStream_t stream) {
    const float* x   = (const float*)d_in[0];
    const float* w   = (const float*)d_in[1];
    const float* wsi = (const float*)d_in[2];
    float* out = (float*)d_out;

    const int K = 4096;
    const int M = in_sizes[0] / K;       // 4096
    const int N = in_sizes[1] / K;       // 16384

    uint8_t* xq  = (uint8_t*)d_ws;                      // M*K bytes
    uint8_t* wq  = xq + (size_t)M * K;                  // N*K bytes
    float*   sxT = (float*)(wq + (size_t)N * K);        // (K/128)*M floats

    int waves = M * (K / BSQ);
    act_quant_kernel<<<dim3(waves / 4), dim3(256), 0, stream>>>(x, xq, sxT, M, K);

    size_t wn = (size_t)N * K;
    weight_quant_kernel<<<dim3((unsigned)(wn / 4 / 256)), dim3(256), 0, stream>>>(w, wq, wn);

    dim3 grid(N / TN, M / TM);
    fp8_gemm_mx<<<grid, dim3(256), 0, stream>>>(xq, wq, sxT, wsi, out, M, N, K);
}

// Round 13
// 463.999 us; speedup vs baseline: 6.7918x; 6.7918x over previous
//
#include <hip/hip_runtime.h>
#include <stdint.h>

#define FP8_MAX 448.0f
#define BSQ 128          // quantization block size
#define TM 128
#define TN 128
#define NKB 32           // K / BSQ

typedef int   i32x4  __attribute__((ext_vector_type(4)));
typedef int   i32x8  __attribute__((ext_vector_type(8)));
typedef float f32x2  __attribute__((ext_vector_type(2)));
typedef float f32x16 __attribute__((ext_vector_type(16)));

typedef const __attribute__((address_space(1))) uint8_t* gptr_t;
typedef __attribute__((address_space(3))) uint8_t* lptr_t;

// 3-bit granule hash: 32-row fragment b128 reads spread evenly over all
// 8 granule-columns -> bank-minimal (verified: 0 conflicts rounds 3-12).
__device__ __forceinline__ int hsw(int row) { return (row ^ (row >> 3)) & 7; }

// ---------------- activation quantization: per (row, 128-block) ----------------
// scales written TRANSPOSED: sxT[kb*M + row]  (lane-linear gather in GEMM stage)
__global__ void act_quant_kernel(const float* __restrict__ x,
                                 uint8_t* __restrict__ xq,
                                 float* __restrict__ sxT,
                                 int M, int K) {
    int gid  = blockIdx.x * blockDim.x + threadIdx.x;
    int wave = gid >> 6;
    int lane = threadIdx.x & 63;
    int nkb  = K / BSQ;
    int row  = wave / nkb;
    int kb   = wave - row * nkb;
    if (row >= M) return;

    const float2 v = *(const float2*)(x + (size_t)row * K + kb * BSQ + lane * 2);
    float am = fmaxf(fabsf(v.x), fabsf(v.y));
#pragma unroll
    for (int off = 32; off >= 1; off >>= 1)
        am = fmaxf(am, __shfl_xor(am, off));

    float s = am / FP8_MAX;                    // matches reference: amax/448 in fp32
    if (lane == 0) sxT[(size_t)kb * M + row] = s;

    float q0 = (am > 0.f) ? v.x / s : 0.f;     // fp32 IEEE division, then RNE->e4m3
    float q1 = (am > 0.f) ? v.y / s : 0.f;
    int packed = __builtin_amdgcn_cvt_pk_fp8_f32(q0, q1, 0, false);
    *(uint16_t*)(xq + (size_t)row * K + kb * BSQ + lane * 2) = (uint16_t)(packed & 0xffff);
}

// ---------------- weight cast fp32(fp8-representable) -> e4m3 bytes ----------------
__global__ void weight_quant_kernel(const float* __restrict__ w,
                                    uint8_t* __restrict__ wq, size_t n) {
    size_t i = ((size_t)blockIdx.x * blockDim.x + threadIdx.x) * 4;
    if (i >= n) return;
    float4 v = *(const float4*)(w + i);
    int lo = __builtin_amdgcn_cvt_pk_fp8_f32(v.x, v.y, 0, false);
    int hi = __builtin_amdgcn_cvt_pk_fp8_f32(v.z, v.w, 0, false);
    *(uint32_t*)(wq + i) = (uint32_t)((lo & 0xffff) | (hi << 16));
}

// ---------------- 128^2 dbuf MX GEMM (champion) + packed fold + read-first head ----------------
// y[m,n] = sum_kb sx[m,kb]*sw[nb,kb] * dot_fp8(x[m,kb*128:+128], w[n,kb*128:+128])
// Changes vs R11 champion (isolated, IEEE-exact):
//  1. fold as f32x2 packed FMA/MUL (64->32 FMA, 32->16 MUL per kb per wave)
//  2. bfr ds_reads issued BEFORE the next-tile STAGE: LDS pipe starts at barrier-
//     clear instead of queuing behind 9 vmem issue slots.
__global__ __launch_bounds__(256, 2)
void fp8_gemm_mx(const uint8_t* __restrict__ Aq,   // [M][K] e4m3
                 const uint8_t* __restrict__ Bq,   // [N][K] e4m3
                 const float*  __restrict__ sxT,   // [K/128][M]  (transposed)
                 const float*  __restrict__ swg,   // [N/128][K/128]
                 float* __restrict__ out,          // [M][N]
                 int M, int N, int K) {
    __shared__ uint8_t As[2][TM * BSQ];      // 2 x 16 KB, granule-swizzled rows
    __shared__ uint8_t Bs[2][TN * BSQ];      // 2 x 16 KB
    __shared__ float   sxs[2][TM];           // 2 x 0.5 KB raw sx row

    const int tid  = threadIdx.x;
    const int lane = tid & 63;
    const int wid  = tid >> 6;
    const int brow = blockIdx.y * TM;
    const int bcol = blockIdx.x * TN;
    const int nb   = bcol >> 7;

    const int wy = wid >> 1, wx = wid & 1;   // 2x2 wave grid, 64x64 per wave
    const int fl = lane & 31, hi = lane >> 5;

    // ---- hoisted staging addresses (kb=0); step offset is uniform kb*BSQ ----
    const uint8_t* gApt[4];
    const uint8_t* gBpt[4];
#pragma unroll
    for (int r = 0; r < 4; ++r) {
        int slot = r * 256 + tid;            // 0..1023 16B-slots
        int row  = slot >> 3;                // 0..127
        int g    = (slot & 7) ^ hsw(row);    // pre-swizzled source granule
        gApt[r] = Aq + (size_t)(brow + row) * K + g * 16;
        gBpt[r] = Bq + (size_t)(bcol + row) * K + g * 16;
    }
    const uint8_t* gSpt = (const uint8_t*)(sxT + brow + wid * 64 + lane);

    // staging: LDS dest linear (wave-uniform base + lane*16), src pre-swizzled
    auto STAGE = [&](int buf, int kb) {
        const size_t ko = (size_t)kb * BSQ;
        const size_t so = (size_t)kb * M * 4;
#pragma unroll
        for (int r = 0; r < 4; ++r) {
            int slot = r * 256 + tid;
            __builtin_amdgcn_global_load_lds((gptr_t)(gApt[r] + ko),
                (lptr_t)(As[buf] + (slot & ~63) * 16), 16, 0, 0);
            __builtin_amdgcn_global_load_lds((gptr_t)(gBpt[r] + ko),
                (lptr_t)(Bs[buf] + (slot & ~63) * 16), 16, 0, 0);
        }
        if (wid < 2) {                       // 128-float scale row, lane x 4B linear
            __builtin_amdgcn_global_load_lds((gptr_t)(gSpt + so),
                (lptr_t)(sxs[buf] + wid * 64), 4, 0, 0);
        }
    };

    const f32x16 zz = {0.f,0.f,0.f,0.f, 0.f,0.f,0.f,0.f,
                       0.f,0.f,0.f,0.f, 0.f,0.f,0.f,0.f};
    f32x2 acc[2][2][8];                      // [fm][fn][q*2+h] -> 64 f32 total
#pragma unroll
    for (int i = 0; i < 2; ++i)
#pragma unroll
        for (int j = 0; j < 2; ++j)
#pragma unroll
            for (int q = 0; q < 8; ++q) acc[i][j][q] = {0.f, 0.f};

    // prologue: stage kb=0, drain once (__syncthreads inserts vmcnt(0))
    STAGE(0, 0);
    __syncthreads();

    for (int kb = 0; kb < NKB; ++kb) {
        const int cur = kb & 1;
        const uint8_t* Ab = As[cur];
        const uint8_t* Bb = Bs[cur];
        const float*   Sb = sxs[cur];

        // ---- B fragments FIRST: LDS pipe starts the moment the barrier clears ----
        i32x8 bfr[2][2];
#pragma unroll
        for (int fn = 0; fn < 2; ++fn) {
            int row = wx * 64 + fn * 32 + fl;
            int hh  = hsw(row);
            const uint8_t* base = Bb + row * BSQ;
#pragma unroll
            for (int kh = 0; kh < 2; ++kh) {
                int g0 = kh * 4 + hi * 2;
                i32x4 lo = *(const i32x4*)(base + (((g0    ) ^ hh) << 4));
                i32x4 h4 = *(const i32x4*)(base + (((g0 + 1) ^ hh) << 4));
                bfr[fn][kh] = (i32x8){lo.x, lo.y, lo.z, lo.w, h4.x, h4.y, h4.z, h4.w};
            }
        }

        // issue next tile's loads: latency hides under this step's compute
        if (kb + 1 < NKB) STAGE(cur ^ 1, kb + 1);

        const float sw = swg[(size_t)nb * NKB + kb];   // block-uniform weight scale

#pragma unroll
        for (int fm = 0; fm < 2; ++fm) {
            int arow = wy * 64 + fm * 32 + fl;
            int hh   = hsw(arow);
            const uint8_t* abase = Ab + arow * BSQ;
            i32x8 afr[2];
#pragma unroll
            for (int kh = 0; kh < 2; ++kh) {
                int g0 = kh * 4 + hi * 2;
                i32x4 lo = *(const i32x4*)(abase + (((g0    ) ^ hh) << 4));
                i32x4 h4 = *(const i32x4*)(abase + (((g0 + 1) ^ hh) << 4));
                afr[kh] = (i32x8){lo.x, lo.y, lo.z, lo.w, h4.x, h4.y, h4.z, h4.w};
            }
            // per-row scales x block-uniform sw, as packed f32x2 (pk_mul)
            f32x2 s2[8];
#pragma unroll
            for (int q = 0; q < 4; ++q) {
                const float* sp = &Sb[wy * 64 + fm * 32 + q * 8 + hi * 4];
                s2[q * 2    ] = *(const f32x2*)(sp    ) * sw;
                s2[q * 2 + 1] = *(const f32x2*)(sp + 2) * sw;
            }

#pragma unroll
            for (int fn = 0; fn < 2; ++fn) {
                // unit HW scales (e8m0 127 -> x1.0); exact fp32 fold below
                f32x16 p = __builtin_amdgcn_mfma_scale_f32_32x32x64_f8f6f4(
                    afr[0], bfr[fn][0], zz, 0, 0, 0, 127, 0, 127);
                p = __builtin_amdgcn_mfma_scale_f32_32x32x64_f8f6f4(
                    afr[1], bfr[fn][1], p, 0, 0, 0, 127, 0, 127);
                // packed fold: 32 v_pk_fma_f32 (two independent IEEE fp32 FMAs)
#pragma unroll
                for (int q = 0; q < 4; ++q)
#pragma unroll
                    for (int h = 0; h < 2; ++h) {
                        f32x2 pq = {p[q * 4 + h * 2], p[q * 4 + h * 2 + 1]};
                        acc[fm][fn][q * 2 + h] += pq * s2[q * 2 + h];
                    }
            }
        }

        // single drain point per step: next tile resident before buffer swap.
        // At 2 blocks/CU the co-resident block computes through this wait.
        __syncthreads();
    }

    // epilogue: C/D 32x32 layout col=lane&31, row=(reg&3)+8*(reg>>2)+4*(lane>>5)
    // nontemporal: 268MB streaming writes must not evict L3-resident fp8 panels
#pragma unroll
    for (int fm = 0; fm < 2; ++fm)
#pragma unroll
        for (int fn = 0; fn < 2; ++fn)
#pragma unroll
            for (int q = 0; q < 4; ++q)
#pragma unroll
                for (int h = 0; h < 2; ++h)
#pragma unroll
                    for (int e = 0; e < 2; ++e) {
                        int row = brow + wy * 64 + fm * 32 + q * 8 + hi * 4 + h * 2 + e;
                        int col = bcol + wx * 64 + fn * 32 + fl;
                        __builtin_nontemporal_store(acc[fm][fn][q * 2 + h][e],
                                                    &out[(size_t)row * N + col]);
                    }
}

extern "C" void kernel_launch(void* const* d_in, const int* in_sizes, int n_in,
                              void* d_out, int out_size, void* d_ws, size_t ws_size,
                              hipStream_t stream) {
    const float* x   = (const float*)d_in[0];
    const float* w   = (const float*)d_in[1];
    const float* wsi = (const float*)d_in[2];
    float* out = (float*)d_out;

    const int K = 4096;
    const int M = in_sizes[0] / K;       // 4096
    const int N = in_sizes[1] / K;       // 16384

    uint8_t* xq  = (uint8_t*)d_ws;                      // M*K bytes
    uint8_t* wq  = xq + (size_t)M * K;                  // N*K bytes
    float*   sxT = (float*)(wq + (size_t)N * K);        // (K/128)*M floats

    int waves = M * (K / BSQ);
    act_quant_kernel<<<dim3(waves / 4), dim3(256), 0, stream>>>(x, xq, sxT, M, K);

    size_t wn = (size_t)N * K;
    weight_quant_kernel<<<dim3((unsigned)(wn / 4 / 256)), dim3(256), 0, stream>>>(w, wq, wn);

    dim3 grid(N / TN, M / TM);
    fp8_gemm_mx<<<grid, dim3(256), 0, stream>>>(xq, wq, sxT, wsi, out, M, N, K);
}